// Round 5
// baseline (521.466 us; speedup 1.0000x reference)
//
#include <hip/hip_runtime.h>
#include <hip/hip_fp16.h>
#include <math.h>

#define T_STEPS 24
#define BATCH   128
#define DGI     256
#define DHI     512
#define S_ITERS 3
#define LAMBDA  0.95f
#define ETA     0.5f
#define EPS_A   1e-6f
#define LN_EPS  1e-5f
#define EPS_N   1e-6f
#define HIST_MAX 23   // at most T-1 stored rank-1 terms

// ---------------------------------------------------------------------------
// Tiled transpose fp32: dst[c*R + r] = src[r*C + c].  R,C multiples of 32.
// ---------------------------------------------------------------------------
__global__ void transpose_k(const float* __restrict__ src, float* __restrict__ dst,
                            int R, int C) {
    __shared__ float tile[32][33];
    const int tx = threadIdx.x & 31;
    const int ty = threadIdx.x >> 5;          // 0..7 (256 threads)
    const int c0 = blockIdx.x * 32;
    const int r0 = blockIdx.y * 32;
    #pragma unroll
    for (int i = 0; i < 32; i += 8)
        tile[ty + i][tx] = src[(size_t)(r0 + ty + i) * C + (c0 + tx)];
    __syncthreads();
    #pragma unroll
    for (int i = 0; i < 32; i += 8)
        dst[(size_t)(c0 + ty + i) * R + (r0 + tx)] = tile[tx][ty + i];
}

// Same but emitting fp16 (for the recurrent W_h GEMV).
__global__ void transpose_h_k(const float* __restrict__ src, __half* __restrict__ dst,
                              int R, int C) {
    __shared__ float tile[32][33];
    const int tx = threadIdx.x & 31;
    const int ty = threadIdx.x >> 5;
    const int c0 = blockIdx.x * 32;
    const int r0 = blockIdx.y * 32;
    #pragma unroll
    for (int i = 0; i < 32; i += 8)
        tile[ty + i][tx] = src[(size_t)(r0 + ty + i) * C + (c0 + tx)];
    __syncthreads();
    #pragma unroll
    for (int i = 0; i < 32; i += 8)
        dst[(size_t)(c0 + ty + i) * R + (r0 + tx)] = __float2half(tile[tx][ty + i]);
}

// ---------------------------------------------------------------------------
// zproj[b][t][i] = sum_j Wg[i][j] * z[t][b][j], via WgT[j][i] (coalesced).
// grid (BATCH, 6), 512 threads; each block: 4 timesteps, weights reused 4x.
// No barriers in the j-loop; pure VALU/L2-stream kernel.
// ---------------------------------------------------------------------------
__global__ __launch_bounds__(512)
void zproj_k(const float* __restrict__ z_seq, const float* __restrict__ WgT,
             float* __restrict__ zp) {
    __shared__ __align__(16) float sh_z[4][DGI];
    const int b    = blockIdx.x;
    const int t0   = blockIdx.y * 4;
    const int tid  = threadIdx.x;
    const int lane = tid & 63;
    const int wave = tid >> 6;
    if (wave < 4) {
        const float4* src =
            (const float4*)(z_seq + ((size_t)(t0 + wave) * BATCH + b) * DGI);
        ((float4*)sh_z[wave])[lane] = src[lane];
    }
    __syncthreads();

    float a0 = 0.f, a1 = 0.f, a2 = 0.f, a3 = 0.f;
    #pragma unroll 8
    for (int j = 0; j < DGI; ++j) {
        const float w = WgT[(size_t)j * DHI + tid];   // lane-consecutive
        a0 = fmaf(w, sh_z[0][j], a0);                 // sh_z[.][j]: broadcast
        a1 = fmaf(w, sh_z[1][j], a1);
        a2 = fmaf(w, sh_z[2][j], a2);
        a3 = fmaf(w, sh_z[3][j], a3);
    }
    zp[((size_t)b * T_STEPS + t0 + 0) * DHI + tid] = a0;
    zp[((size_t)b * T_STEPS + t0 + 1) * DHI + tid] = a1;
    zp[((size_t)b * T_STEPS + t0 + 2) * DHI + tid] = a2;
    zp[((size_t)b * T_STEPS + t0 + 3) * DHI + tid] = a3;
}

// ---------------------------------------------------------------------------
// Recurrence. One block per batch element, 512 threads.
// ZP=true: WhH is fp16 TRANSPOSED WhT[j][i]; zp holds precomputed Wg.z.
//   GEMV: thread (i8=lane, jg=wave): j in [jg*64, jg*64+64), one float4 load
//   = 8 consecutive-i halves per j; fp32 accumulate; 8-way partial combine.
// A is rank-1 factorized with an incrementally-maintained Gram matrix.
// ---------------------------------------------------------------------------
template<bool ZP>
__global__ __launch_bounds__(512)
void corernn_kernel(const float* __restrict__ z_seq,
                    const float* __restrict__ Wh,    // fallback: row-major fp32
                    const __half* __restrict__ WhH,  // ZP: WhT[j][i] fp16
                    const float* __restrict__ Wg,
                    const float* __restrict__ b_h,
                    const float* __restrict__ gamma,
                    const float* __restrict__ beta,
                    const float* __restrict__ alpha_fw,
                    const float* __restrict__ zp,
                    float* __restrict__ out) {
    __shared__ __align__(16) float sh_hist[HIST_MAX][DHI];
    __shared__ __align__(16) float sh_hs[2][DHI];      // ping-pong h buffers
    __shared__ __align__(16) float sh_G[HIST_MAX][64]; // Gram, padded cols
    __shared__ __align__(16) float sh_part[8][DHI];    // GEMV jg-partials (16KB)
    __shared__ float  sh_coef[32];
    __shared__ float  sh_dot[32];
    __shared__ float2 sh_red[8];
    __shared__ __align__(16) float sh_z[DGI];          // fallback path only

    const int tid  = threadIdx.x;
    const int lane = tid & 63;
    const int wave = tid >> 6;
    const int b    = blockIdx.x;

    const float bh_r = b_h[tid];
    const float g_r  = gamma[tid];
    const float bt_r = beta[tid];

    float kpow;
    {
        const float a  = alpha_fw[0];
        const float ax = fabsf(a);
        const float sp = (ax > 20.f) ? ax : log1pf(expf(ax));
        kpow = (a >= 0.f) ? (1.f + sp) : (1.f / (1.f + sp));
    }

    // zero Gram (padded columns must be 0, not poison)
    for (int i = tid; i < HIST_MAX * 64; i += DHI) ((float*)sh_G)[i] = 0.f;
    if (!ZP) { if (tid < DGI) sh_z[tid] = z_seq[(size_t)b * DGI + tid]; }
    __syncthreads();

    int   p = 0;          // parity of the buffer holding the current h
    float hs_i = 0.f, hbase_i = 0.f;

    for (int t = 0; t < T_STEPS; ++t) {
        // ---- GEMV: h_base = b_h + Wh.h + Wg.z   (h==0 at t==0)
        if (ZP) {
            const float zval = zp[((size_t)b * T_STEPS + t) * DHI + tid];
            if (t > 0) {
                // fp16 transposed GEMV: i8=lane owns dims [8*lane, 8*lane+8),
                // jg=wave covers j in [wave*64, wave*64+64)
                float acc[8];
                #pragma unroll
                for (int k = 0; k < 8; ++k) acc[k] = 0.f;
                const float4* wp = (const float4*)WhH;  // row j = 64 float4
                const float*  hrow = sh_hs[p];
                const int jlo = wave * 64;
                #pragma unroll 8
                for (int jj = 0; jj < 64; ++jj) {
                    const int j = jlo + jj;
                    const float hj = hrow[j];           // wave-uniform broadcast
                    const float4 wv = wp[(size_t)j * 64 + lane];
                    const __half2* hp = (const __half2*)&wv;
                    #pragma unroll
                    for (int m = 0; m < 4; ++m) {
                        const float2 f = __half22float2(hp[m]);
                        acc[2 * m    ] = fmaf(f.x, hj, acc[2 * m    ]);
                        acc[2 * m + 1] = fmaf(f.y, hj, acc[2 * m + 1]);
                    }
                }
                float4* pr = (float4*)&sh_part[wave][8 * lane];
                pr[0] = make_float4(acc[0], acc[1], acc[2], acc[3]);
                pr[1] = make_float4(acc[4], acc[5], acc[6], acc[7]);
                __syncthreads();                          // barrier A
                float sum = 0.f;
                #pragma unroll
                for (int g = 0; g < 8; ++g) sum += sh_part[g][tid]; // stride-1/lane
                hbase_i = bh_r + zval + sum;
            } else {
                hbase_i = bh_r + zval;
            }
        } else {
            float a0 = bh_r, a1 = 0.f, a2 = 0.f, a3 = 0.f;
            {
                const float4* wrow = (const float4*)(Wg + (size_t)tid * DGI);
                const float4* z4   = (const float4*)sh_z;
                #pragma unroll 4
                for (int j4 = 0; j4 < DGI / 4; ++j4) {
                    const float4 w = wrow[j4];
                    const float4 h = z4[j4];
                    a0 = fmaf(w.x, h.x, a0); a1 = fmaf(w.y, h.y, a1);
                    a2 = fmaf(w.z, h.z, a2); a3 = fmaf(w.w, h.w, a3);
                }
            }
            if (t > 0) {
                const float4* wrow = (const float4*)(Wh + (size_t)tid * DHI);
                const float4* h4   = (const float4*)sh_hs[p];
                #pragma unroll 4
                for (int j4 = 0; j4 < DHI / 4; ++j4) {
                    const float4 w = wrow[j4];
                    const float4 h = h4[j4];
                    a0 = fmaf(w.x, h.x, a0); a1 = fmaf(w.y, h.y, a1);
                    a2 = fmaf(w.z, h.z, a2); a3 = fmaf(w.w, h.w, a3);
                }
            }
            hbase_i = (a0 + a1) + (a2 + a3);
        }
        hs_i = fmaxf(hbase_i, 0.f);
        p ^= 1;
        sh_hs[p][tid] = hs_i;
        __syncthreads();                                  // barrier 1

        // ---- inner iterations (t==0: A==0 -> y==h_base every iter -> 1 pass)
        const int niter = (t == 0) ? 1 : S_ITERS;
        for (int it = 0; it < niter; ++it) {
            const float* hcur = sh_hs[p];
            float h8[8];
            #pragma unroll
            for (int q = 0; q < 8; ++q) h8[q] = hcur[lane + 64 * q];

            // dots phase: wave-split over s in [0..t]; s==t is the self-dot
            for (int s = wave; s <= t; s += 8) {
                float d = 0.f;
                if (s == t) {
                    #pragma unroll
                    for (int q = 0; q < 8; ++q) d = fmaf(h8[q], h8[q], d);
                } else {
                    const float* vr = sh_hist[s];
                    #pragma unroll
                    for (int q = 0; q < 8; ++q) d = fmaf(vr[lane + 64 * q], h8[q], d);
                }
                #pragma unroll
                for (int off = 32; off > 0; off >>= 1) d += __shfl_xor(d, off, 64);
                if (lane == 0) sh_dot[s] = d;
            }
            __syncthreads();                              // barrier 2

            // scalar phase (per-thread redundant; broadcast LDS reads only)
            float dl = 0.f, w_l = 0.f;
            if (lane < t) { dl = sh_dot[lane]; w_l = sh_coef[lane] * dl; }

            float gsum = 0.f, Ah = 0.f;
            for (int s = 0; s < t; ++s) {
                const float ws = sh_coef[s] * sh_dot[s];  // uniform (broadcast)
                gsum = fmaf(ws, sh_G[s][lane], gsum);
                Ah   = fmaf(ws, sh_hist[s][tid], Ah);
            }
            float pa = w_l * dl;                          // -> h.Ah
            float pb = w_l * gsum;                        // -> |Ah|^2
            #pragma unroll
            for (int off = 32; off > 0; off >>= 1) {
                pa += __shfl_xor(pa, off, 64);
                pb += __shfl_xor(pb, off, 64);
            }
            const float n1 = fmaxf(sqrtf(sh_dot[t]), EPS_N);
            const float n2 = fmaxf(sqrtf(fmaxf(pb, 0.f)), EPS_N);
            float R = pa / (n1 * n2);
            R = fminf(fmaxf(R, 0.f), 1.f);
            const float alpha = 1.f - __powf(1.f - R, kpow);

            const float y = (1.f - alpha * alpha) * hbase_i + alpha * Ah;

            // LayerNorm reduction: one per-wave butterfly + one barrier
            float q0 = y, q1 = y * y;
            #pragma unroll
            for (int off = 32; off > 0; off >>= 1) {
                q0 += __shfl_xor(q0, off, 64);
                q1 += __shfl_xor(q1, off, 64);
            }
            if (lane == 0) sh_red[wave] = make_float2(q0, q1);
            __syncthreads();                              // barrier 3

            float s0 = 0.f, s1 = 0.f;
            #pragma unroll
            for (int w = 0; w < 8; ++w) {
                const float2 r = sh_red[w];
                s0 += r.x; s1 += r.y;
            }
            const float mean = s0 * (1.f / DHI);
            const float var  = fmaf(s1, 1.f / DHI, -mean * mean);
            const float rstd = rsqrtf(var + LN_EPS);
            hs_i = fmaxf(fmaf((y - mean) * rstd, g_r, bt_r), 0.f);
            p ^= 1;
            sh_hs[p][tid] = hs_i;
            // fallback path: stage next timestep's z before the barrier
            if (!ZP && it == niter - 1 && t + 1 < T_STEPS && tid < DGI)
                sh_z[tid] = z_seq[((size_t)(t + 1) * BATCH + b) * DGI + tid];
            __syncthreads();                              // barrier 4
        }

        if (t < T_STEPS - 1) {
            // history append: Gram row + coef; overlaps with next GEMV
            // (visibility for step t+1 readers via t+1's barriers A/1)
            const float* hcur = sh_hs[p];
            float h8[8];
            #pragma unroll
            for (int q = 0; q < 8; ++q) h8[q] = hcur[lane + 64 * q];
            for (int s = wave; s <= t; s += 8) {
                float d = 0.f;
                if (s == t) {
                    #pragma unroll
                    for (int q = 0; q < 8; ++q) d = fmaf(h8[q], h8[q], d);
                } else {
                    const float* vr = sh_hist[s];
                    #pragma unroll
                    for (int q = 0; q < 8; ++q) d = fmaf(vr[lane + 64 * q], h8[q], d);
                }
                #pragma unroll
                for (int off = 32; off > 0; off >>= 1) d += __shfl_xor(d, off, 64);
                if (lane == 0) {
                    if (s == t) {
                        sh_G[t][t] = d;
                        sh_coef[t] = ETA / (d + EPS_A);
                    } else {
                        sh_G[t][s] = d;
                        sh_G[s][t] = d;
                    }
                }
            }
            if (tid < t) sh_coef[tid] *= LAMBDA;   // lambda-decay existing terms
            sh_hist[t][tid] = hs_i;
        } else {
            out[(size_t)b * DHI + tid] = hs_i;
        }
    }
}

extern "C" void kernel_launch(void* const* d_in, const int* in_sizes, int n_in,
                              void* d_out, int out_size, void* d_ws, size_t ws_size,
                              hipStream_t stream) {
    const float* z_seq    = (const float*)d_in[0];
    const float* W_h      = (const float*)d_in[1];
    const float* W_g      = (const float*)d_in[2];
    const float* b_h      = (const float*)d_in[3];
    const float* gamma    = (const float*)d_in[4];
    const float* beta     = (const float*)d_in[5];
    const float* alpha_fw = (const float*)d_in[6];
    float* out = (float*)d_out;

    const size_t wgt_elems = (size_t)DGI * DHI;              // 512 KB fp32
    const size_t zp_elems  = (size_t)BATCH * T_STEPS * DHI;  // 6 MB fp32
    const size_t wht_elems = (size_t)DHI * DHI;              // 512 KB fp16
    const size_t needed = (wgt_elems + zp_elems) * sizeof(float)
                        + wht_elems * sizeof(__half);
    if (ws_size >= needed) {
        float*  WgT  = (float*)d_ws;
        float*  zp   = WgT + wgt_elems;
        __half* WhTh = (__half*)(zp + zp_elems);
        // WgT[j][i] <- Wg[i][j]  (src R=DHI rows, C=DGI cols)
        transpose_k<<<dim3(DGI / 32, DHI / 32), 256, 0, stream>>>(W_g, WgT, DHI, DGI);
        // WhT[j][i] fp16 <- Wh[i][j]
        transpose_h_k<<<dim3(DHI / 32, DHI / 32), 256, 0, stream>>>(W_h, WhTh, DHI, DHI);
        zproj_k<<<dim3(BATCH, T_STEPS / 4), 512, 0, stream>>>(z_seq, WgT, zp);
        corernn_kernel<true><<<BATCH, DHI, 0, stream>>>(z_seq, nullptr, WhTh, W_g,
                                                        b_h, gamma, beta, alpha_fw,
                                                        zp, out);
    } else {
        corernn_kernel<false><<<BATCH, DHI, 0, stream>>>(z_seq, W_h, nullptr, W_g,
                                                         b_h, gamma, beta, alpha_fw,
                                                         nullptr, out);
    }
}